// Round 12
// baseline (2674.765 us; speedup 1.0000x reference)
//
#include <hip/hip_runtime.h>
#include <hip/hip_bf16.h>
#include <math.h>

#define NROWS 16384
#define HID 64
#define KSPLIT 8
#define KCH (NROWS / KSPLIT)   // 2048
#define STK 128                // stage depth in k-floats
#define NSTAGE (KCH / STK)     // 16

typedef __attribute__((ext_vector_type(8))) __bf16 bf16x8;
typedef __attribute__((ext_vector_type(4))) float f32x4;
typedef __attribute__((ext_vector_type(4))) int i32x4;

__device__ inline f32x4 mfma16(bf16x8 a, bf16x8 b, f32x4 c) {
    return __builtin_amdgcn_mfma_f32_16x16x32_bf16(a, b, c, 0, 0, 0);
}

__device__ inline void split8v(const f32x4 v0, const f32x4 v1, bf16x8& h, bf16x8& l) {
    float f[8] = {v0[0], v0[1], v0[2], v0[3], v1[0], v1[1], v1[2], v1[3]};
#pragma unroll
    for (int j = 0; j < 8; ++j) {
        __bf16 hh = (__bf16)f[j];
        h[j] = hh;
        l[j] = (__bf16)(f[j] - (float)hh);
    }
}

// ---------------------------------------------------------------------------
// pack_b: x [16384,64] fp32 row-major  ->  MFMA B-fragment-ordered bf16 hi/lo.
// ---------------------------------------------------------------------------
__global__ __launch_bounds__(256) void pack_b(const float* __restrict__ x,
                                              __bf16* __restrict__ hi,
                                              __bf16* __restrict__ lo) {
    __shared__ float tile[32 * 64];
    const int kb = blockIdx.x;  // 0..511, 32 k-rows each
    const f32x4* src = (const f32x4*)(x + (size_t)kb * 32 * 64);
    f32x4* dst = (f32x4*)tile;
    dst[threadIdx.x] = src[threadIdx.x];
    dst[threadIdx.x + 256] = src[threadIdx.x + 256];
    __syncthreads();
    const int t = threadIdx.x >> 6;    // n-tile 0..3
    const int l = threadIdx.x & 63;    // consumer lane
    const int col = (t << 4) + (l & 15);
    const int krow = (l >> 4) * 8;
    bf16x8 h8, l8;
#pragma unroll
    for (int j = 0; j < 8; ++j) {
        float v = tile[(krow + j) * 64 + col];
        __bf16 hh = (__bf16)v;
        h8[j] = hh;
        l8[j] = (__bf16)(v - (float)hh);
    }
    const size_t base = (((size_t)kb * 4 + t) * 64 + l) * 8;
    *(bf16x8*)(hi + base) = h8;
    *(bf16x8*)(lo + base) = l8;
}

// ---------------------------------------------------------------------------
// gemm_partial: unchanged from r9 (best 588 us). LDS-staged contiguous
// A-reads, swizzled ds_read, T14 async split, cross-wave K-reduction.
// ---------------------------------------------------------------------------
__global__ __launch_bounds__(256, 4) void gemm_partial(const float* __restrict__ adj,
                                                       const __bf16* __restrict__ Bhi,
                                                       const __bf16* __restrict__ Blo,
                                                       float* __restrict__ partial) {
    __shared__ char lds_raw[32768];  // 2 x 16KB stage buffers; reused as red

    const int tid = threadIdx.x;
    const int lane = tid & 63;
    const int wv = tid >> 6;          // wave 0..3 -> k-substep within stage
    const int rt = blockIdx.x & 511;  // row-tile (32 rows)
    const int ks = blockIdx.x >> 9;   // k-split 0..7
    const int rbase = rt * 32;
    const int rq = lane & 15;
    const int kq = lane >> 4;

    f32x4 acc[2][4];
#pragma unroll
    for (int g = 0; g < 2; ++g)
#pragma unroll
        for (int t = 0; t < 4; ++t) acc[g][t] = f32x4{0.f, 0.f, 0.f, 0.f};

    const int srow = tid >> 5;
    const int scol = tid & 31;
    const int sw = (srow & 7) << 4;
    const float* agbase = adj + (size_t)(rbase + srow) * NROWS + ks * KCH + scol * 4;

    f32x4 areg[4];
#pragma unroll
    for (int i = 0; i < 4; ++i)
        areg[i] = *(const f32x4*)(agbase + (size_t)i * 8 * NROWS);
#pragma unroll
    for (int i = 0; i < 4; ++i)
        *(f32x4*)(lds_raw + (srow + 8 * i) * 512 + ((scol * 16) ^ sw)) = areg[i];
    __syncthreads();

    for (int s = 0; s < NSTAGE; ++s) {
        const int buf = s & 1;
        if (s + 1 < NSTAGE) {
#pragma unroll
            for (int i = 0; i < 4; ++i)
                areg[i] = *(const f32x4*)(agbase + (size_t)i * 8 * NROWS +
                                          (s + 1) * STK);
        }
        {
            const size_t bb = (size_t)(ks * 64 + s * 4 + wv) * 2048 + (size_t)lane * 8;
            bf16x8 bh[4], bl[4];
#pragma unroll
            for (int t = 0; t < 4; ++t) {
                bh[t] = *(const bf16x8*)(Bhi + bb + (size_t)t * 512);
                bl[t] = *(const bf16x8*)(Blo + bb + (size_t)t * 512);
            }
            char* base = lds_raw + buf * 16384;
            const int kb = wv * 128 + kq * 32;
            const int rsw = (rq & 7) << 4;
            f32x4 a0lo = *(const f32x4*)(base + rq * 512 + (kb ^ rsw));
            f32x4 a0hi = *(const f32x4*)(base + rq * 512 + ((kb + 16) ^ rsw));
            f32x4 a1lo = *(const f32x4*)(base + (16 + rq) * 512 + (kb ^ rsw));
            f32x4 a1hi = *(const f32x4*)(base + (16 + rq) * 512 + ((kb + 16) ^ rsw));
            bf16x8 ah0, al0, ah1, al1;
            split8v(a0lo, a0hi, ah0, al0);
            split8v(a1lo, a1hi, ah1, al1);
#pragma unroll
            for (int t = 0; t < 4; ++t) {
                acc[0][t] = mfma16(ah0, bh[t], acc[0][t]);
                acc[0][t] = mfma16(ah0, bl[t], acc[0][t]);
                acc[0][t] = mfma16(al0, bh[t], acc[0][t]);
                acc[1][t] = mfma16(ah1, bh[t], acc[1][t]);
                acc[1][t] = mfma16(ah1, bl[t], acc[1][t]);
                acc[1][t] = mfma16(al1, bh[t], acc[1][t]);
            }
        }
        if (s + 1 < NSTAGE) {
#pragma unroll
            for (int i = 0; i < 4; ++i)
                *(f32x4*)(lds_raw + (buf ^ 1) * 16384 + (srow + 8 * i) * 512 +
                          ((scol * 16) ^ sw)) = areg[i];
        }
        __syncthreads();
    }

    // C/D layout: col = lane&15, row = (lane>>4)*4 + reg   [m89-verified]
    float(*red)[32][64] = (float(*)[32][64])lds_raw;
#pragma unroll
    for (int g = 0; g < 2; ++g)
#pragma unroll
        for (int t = 0; t < 4; ++t)
#pragma unroll
            for (int r = 0; r < 4; ++r)
                red[wv][g * 16 + kq * 4 + r][t * 16 + rq] = acc[g][t][r];
    __syncthreads();

    const int row = tid >> 3;
    const int c0 = (tid & 7) * 8;
    f32x4 s0 = f32x4{0.f, 0.f, 0.f, 0.f};
    f32x4 s1 = f32x4{0.f, 0.f, 0.f, 0.f};
#pragma unroll
    for (int w = 0; w < 4; ++w) {
        s0 += *(const f32x4*)&red[w][row][c0];
        s1 += *(const f32x4*)&red[w][row][c0 + 4];
    }
    float* pp = partial + (size_t)ks * (NROWS * HID) + (size_t)(rbase + row) * HID + c0;
    __builtin_nontemporal_store(s0, (f32x4*)pp);
    __builtin_nontemporal_store(s1, (f32x4*)(pp + 4));
}

// ---------------------------------------------------------------------------
// reduce_dense: agg_r = sum_ks partial[ks][r]; x_out[r] = tanh([agg_r|x_r] @ W)
// ---------------------------------------------------------------------------
__global__ __launch_bounds__(256) void reduce_dense(const float* __restrict__ partial,
                                                    const float* __restrict__ xin,
                                                    const float* __restrict__ W,
                                                    float* __restrict__ xout) {
    __shared__ float wsm[128 * 64];  // 32 KB
    const f32x4* wsrc = (const f32x4*)W;
    f32x4* wdst = (f32x4*)wsm;
#pragma unroll
    for (int i = 0; i < 8; ++i) wdst[threadIdx.x + 256 * i] = wsrc[threadIdx.x + 256 * i];
    __syncthreads();

    const int lane = threadIdx.x & 63;
    const int wv = threadIdx.x >> 6;
    const int r0 = blockIdx.x * 32 + wv * 8;
#pragma unroll 2
    for (int i = 0; i < 8; ++i) {
        const int r = r0 + i;
        float av = 0.f;
#pragma unroll
        for (int ks = 0; ks < KSPLIT; ++ks)
            av += partial[(size_t)ks * (NROWS * HID) + (size_t)r * HID + lane];
        const float xv = xin[(size_t)r * HID + lane];
        float z = 0.f;
#pragma unroll
        for (int j = 0; j < 64; ++j) z += __shfl(av, j) * wsm[j * 64 + lane];
#pragma unroll
        for (int j = 0; j < 64; ++j) z += __shfl(xv, j) * wsm[(64 + j) * 64 + lane];
        xout[(size_t)r * HID + lane] = tanhf(z);
    }
}

// ---------------------------------------------------------------------------
// probe_a (MEASUREMENT, this round only): A-loads in the GEMM's exact shape
// (1024 blocks = 4/CU, 4 waves x 32 rows, 128B per row per 32-k step), no B,
// no MFMA. 5 passes (k-chunk rotated per pass to kill L2/L3 carryover).
// Discriminates access-class ceiling (~1340us @ 4 TB/s) vs streaming-fast
// (~865us @ 6.2 TB/s).
// ---------------------------------------------------------------------------
__global__ __launch_bounds__(256) void probe_a(const float* __restrict__ adj,
                                               float* __restrict__ sink) {
    const int lane = threadIdx.x & 63;
    const int wv = threadIdx.x >> 6;
    const int rt = blockIdx.x & 127;
    const int ks0 = blockIdx.x >> 7;
    const int rbase = rt * 128 + wv * 32;
    const int rq = lane & 15;
    const int kq = lane >> 4;
    const float* a0p = adj + (size_t)(rbase + rq) * NROWS + kq * 8;
    const float* a1p = a0p + (size_t)16 * NROWS;
    f32x4 acc0 = f32x4{0.f, 0.f, 0.f, 0.f};
    f32x4 acc1 = f32x4{0.f, 0.f, 0.f, 0.f};
#pragma unroll 1
    for (int p = 0; p < 5; ++p) {
        const int koff = ((ks0 + p) & 7) * KCH;
#pragma unroll 1
        for (int kk = 0; kk < KCH; kk += 32) {
            const f32x4* a0 = (const f32x4*)(a0p + koff + kk);
            const f32x4* a1 = (const f32x4*)(a1p + koff + kk);
            acc0 += a0[0] + a0[1];
            acc1 += a1[0] + a1[1];
        }
    }
    f32x4 s = acc0 + acc1;
    sink[(size_t)blockIdx.x * 256 + threadIdx.x] = s[0] + s[1] + s[2] + s[3];
}

// ---------------------------------------------------------------------------
// probe_ab (MEASUREMENT, this round only): probe_a + the GEMM's B-load stream
// (8 x bf16x8 per wave-step from the packed L2-resident B), no MFMA/split.
// probe_a fast + probe_ab slow => B-loads poison A delivery.
// ---------------------------------------------------------------------------
__global__ __launch_bounds__(256) void probe_ab(const float* __restrict__ adj,
                                                const __bf16* __restrict__ Bhi,
                                                const __bf16* __restrict__ Blo,
                                                float* __restrict__ sink) {
    const int lane = threadIdx.x & 63;
    const int wv = threadIdx.x >> 6;
    const int rt = blockIdx.x & 127;
    const int ks0 = blockIdx.x >> 7;
    const int rbase = rt * 128 + wv * 32;
    const int rq = lane & 15;
    const int kq = lane >> 4;
    const float* a0p = adj + (size_t)(rbase + rq) * NROWS + kq * 8;
    const float* a1p = a0p + (size_t)16 * NROWS;
    f32x4 acc0 = f32x4{0.f, 0.f, 0.f, 0.f};
    f32x4 acc1 = f32x4{0.f, 0.f, 0.f, 0.f};
    i32x4 bacc = i32x4{0, 0, 0, 0};
#pragma unroll 1
    for (int p = 0; p < 5; ++p) {
        const int ks = (ks0 + p) & 7;
        const int koff = ks * KCH;
#pragma unroll 1
        for (int kk = 0; kk < KCH; kk += 32) {
            const size_t bb = (size_t)(ks * 64 + (kk >> 5)) * 2048 + (size_t)lane * 8;
#pragma unroll
            for (int t = 0; t < 4; ++t) {
                bacc ^= *(const i32x4*)(Bhi + bb + (size_t)t * 512);
                bacc ^= *(const i32x4*)(Blo + bb + (size_t)t * 512);
            }
            const f32x4* a0 = (const f32x4*)(a0p + koff + kk);
            const f32x4* a1 = (const f32x4*)(a1p + koff + kk);
            acc0 += a0[0] + a0[1];
            acc1 += a1[0] + a1[1];
        }
    }
    f32x4 s = acc0 + acc1;
    sink[(size_t)blockIdx.x * 256 + threadIdx.x] =
        s[0] + s[1] + s[2] + s[3] + (float)(bacc[0] ^ bacc[1] ^ bacc[2] ^ bacc[3]);
}

extern "C" void kernel_launch(void* const* d_in, const int* in_sizes, int n_in,
                              void* d_out, int out_size, void* d_ws, size_t ws_size,
                              hipStream_t stream) {
    const float* x0 = (const float*)d_in[0];   // user_embs [16384,64]
    const float* adj = (const float*)d_in[1];  // adj [16384,16384]
    const float* W = (const float*)d_in[2];    // W [2,128,64]
    float* out = (float*)d_out;

    char* ws = (char*)d_ws;
    __bf16* Bhi = (__bf16*)(ws);                       // 2 MB
    __bf16* Blo = (__bf16*)(ws + (2u << 20));          // 2 MB
    float* partial = (float*)(ws + (4u << 20));        // 32 MB (8 x 4 MB)
    float* x1 = (float*)(ws + (36u << 20));            // 4 MB
    float* sink = (float*)(ws + (40u << 20));          // 2 MB probe sink

    // hop 0
    pack_b<<<512, 256, 0, stream>>>(x0, Bhi, Blo);
    gemm_partial<<<KSPLIT * 512, 256, 0, stream>>>(adj, Bhi, Blo, partial);
    reduce_dense<<<512, 256, 0, stream>>>(partial, x0, W, x1);
    // hop 1
    pack_b<<<512, 256, 0, stream>>>(x1, Bhi, Blo);
    gemm_partial<<<KSPLIT * 512, 256, 0, stream>>>(adj, Bhi, Blo, partial);
    reduce_dense<<<512, 256, 0, stream>>>(partial, x1, W + 128 * 64, out);
    // measurement probes (appended last; removed next round)
    probe_a<<<1024, 256, 0, stream>>>(adj, sink);
    probe_ab<<<1024, 256, 0, stream>>>(adj, Bhi, Blo, sink);
}

// Round 13
// 499.298 us; speedup vs baseline: 5.3571x; 5.3571x over previous
//
#include <hip/hip_runtime.h>
#include <hip/hip_bf16.h>
#include <math.h>

#define NROWS 16384
#define HID 64
#define KSPLIT 8
#define KCH (NROWS / KSPLIT)  // 2048

typedef __attribute__((ext_vector_type(8))) __bf16 bf16x8;
typedef __attribute__((ext_vector_type(4))) float f32x4;

__device__ inline f32x4 mfma16(bf16x8 a, bf16x8 b, f32x4 c) {
    return __builtin_amdgcn_mfma_f32_16x16x32_bf16(a, b, c, 0, 0, 0);
}

__device__ inline void split8v(const f32x4 v0, const f32x4 v1, bf16x8& h, bf16x8& l) {
    float f[8] = {v0[0], v0[1], v0[2], v0[3], v1[0], v1[1], v1[2], v1[3]};
#pragma unroll
    for (int j = 0; j < 8; ++j) {
        __bf16 hh = (__bf16)f[j];
        h[j] = hh;
        l[j] = (__bf16)(f[j] - (float)hh);
    }
}

// ---------------------------------------------------------------------------
// pack_b: x [16384,64] fp32 row-major  ->  MFMA B-fragment-ordered bf16 hi/lo.
// Packed index: (((kb*4 + t)*64 + lane)*8 + j)
//   holds x[kb*32 + (lane>>4)*8 + j][t*16 + (lane&15)]
// ---------------------------------------------------------------------------
__global__ __launch_bounds__(256) void pack_b(const float* __restrict__ x,
                                              __bf16* __restrict__ hi,
                                              __bf16* __restrict__ lo) {
    __shared__ float tile[32 * 64];
    const int kb = blockIdx.x;  // 0..511, 32 k-rows each
    const f32x4* src = (const f32x4*)(x + (size_t)kb * 32 * 64);
    f32x4* dst = (f32x4*)tile;
    dst[threadIdx.x] = src[threadIdx.x];
    dst[threadIdx.x + 256] = src[threadIdx.x + 256];
    __syncthreads();
    const int t = threadIdx.x >> 6;    // n-tile 0..3
    const int l = threadIdx.x & 63;    // consumer lane
    const int col = (t << 4) + (l & 15);
    const int krow = (l >> 4) * 8;
    bf16x8 h8, l8;
#pragma unroll
    for (int j = 0; j < 8; ++j) {
        float v = tile[(krow + j) * 64 + col];
        __bf16 hh = (__bf16)v;
        h8[j] = hh;
        l8[j] = (__bf16)(v - (float)hh);
    }
    const size_t base = (((size_t)kb * 4 + t) * 64 + l) * 8;
    *(bf16x8*)(hi + base) = h8;
    *(bf16x8*)(lo + base) = l8;
}

// ---------------------------------------------------------------------------
// gemm_partial: partial[ks] = adj[:, ks-chunk] @ x[ks-chunk, :]
// B-INTERFERENCE FIX (r12 probes: pure-A in gemm shape = 6.16 TB/s; adding
// the 8-per-step B-load stream = 4.4 TB/s -> B VMEM slots throttle A).
// Amortize B over 2x rows: each wave owns 64 rows (4 x 16-row groups), so a
// 32-k step is 8 B-instr + 8 A-instr + 48 MFMA (was 8:4:24). Block = 4 waves
// x 64 rows = 256 rows, all waves share the k-range (B L1-shared).
// blockIdx = ks*64 + rt; grid 512 = 2 blocks/CU (8 waves/CU; step period
// >> HBM latency so TLP is ample -- r6/r7 occupancy nulls).
// adj loads plain (L1 merges half-line pairs; nt double-fetched, r3/r4).
// Partial stores nt (no reuse, keep L2 for B).
// ---------------------------------------------------------------------------
__global__ __launch_bounds__(256, 2) void gemm_partial(const float* __restrict__ adj,
                                                       const __bf16* __restrict__ Bhi,
                                                       const __bf16* __restrict__ Blo,
                                                       float* __restrict__ partial) {
    const int lane = threadIdx.x & 63;
    const int wv = threadIdx.x >> 6;   // wave -> 64-row group
    const int rt = blockIdx.x & 63;    // row-tile 0..63 (256 rows each)
    const int ks = blockIdx.x >> 6;    // k-split 0..7
    const int rbase = rt * 256 + wv * 64;
    const int rq = lane & 15;          // A row within 16-row group
    const int kq = lane >> 4;          // k-quarter 0..3

    f32x4 acc[4][4];
#pragma unroll
    for (int g = 0; g < 4; ++g)
#pragma unroll
        for (int t = 0; t < 4; ++t) acc[g][t] = f32x4{0.f, 0.f, 0.f, 0.f};

    const float* ap = adj + (size_t)(rbase + rq) * NROWS + ks * KCH + kq * 8;
    const int kk0 = ks * KCH;

    for (int kk = 0; kk < KCH; kk += 32) {
        // A: 4 groups x 2 instrs, issued first (oldest in vmcnt queue)
        f32x4 av[4][2];
#pragma unroll
        for (int g = 0; g < 4; ++g) {
            const f32x4* a = (const f32x4*)(ap + (size_t)(g * 16) * NROWS + kk);
            av[g][0] = a[0];
            av[g][1] = a[1];
        }
        // B fragments (L2-resident packed bf16), 8 x 16B, wave-shared
        const size_t bb = ((size_t)((kk0 + kk) >> 5) * 4) * 512 + (size_t)lane * 8;
        bf16x8 bh[4], bl[4];
#pragma unroll
        for (int t = 0; t < 4; ++t) {
            bh[t] = *(const bf16x8*)(Bhi + bb + (size_t)t * 512);
            bl[t] = *(const bf16x8*)(Blo + bb + (size_t)t * 512);
        }
        // consume: 48 MFMA
#pragma unroll
        for (int g = 0; g < 4; ++g) {
            bf16x8 ah, al;
            split8v(av[g][0], av[g][1], ah, al);
#pragma unroll
            for (int t = 0; t < 4; ++t) {
                acc[g][t] = mfma16(ah, bh[t], acc[g][t]);
                acc[g][t] = mfma16(ah, bl[t], acc[g][t]);
                acc[g][t] = mfma16(al, bh[t], acc[g][t]);
            }
        }
    }

    // C/D layout: col = lane&15, row = (lane>>4)*4 + reg   [m89-verified]
    float* pp = partial + (size_t)ks * (NROWS * HID) + (size_t)rbase * HID;
#pragma unroll
    for (int g = 0; g < 4; ++g)
#pragma unroll
        for (int t = 0; t < 4; ++t)
#pragma unroll
            for (int r = 0; r < 4; ++r)
                __builtin_nontemporal_store(acc[g][t][r],
                    pp + (g * 16 + kq * 4 + r) * HID + t * 16 + rq);
}

// ---------------------------------------------------------------------------
// reduce_dense: agg_r = sum_ks partial[ks][r]; x_out[r] = tanh([agg_r|x_r] @ W)
// W [128,64] staged in LDS; lane = output column; row values via __shfl.
// ---------------------------------------------------------------------------
__global__ __launch_bounds__(256) void reduce_dense(const float* __restrict__ partial,
                                                    const float* __restrict__ xin,
                                                    const float* __restrict__ W,
                                                    float* __restrict__ xout) {
    __shared__ float wsm[128 * 64];  // 32 KB
    const f32x4* wsrc = (const f32x4*)W;
    f32x4* wdst = (f32x4*)wsm;
#pragma unroll
    for (int i = 0; i < 8; ++i) wdst[threadIdx.x + 256 * i] = wsrc[threadIdx.x + 256 * i];
    __syncthreads();

    const int lane = threadIdx.x & 63;
    const int wv = threadIdx.x >> 6;
    const int r0 = blockIdx.x * 32 + wv * 8;
#pragma unroll 2
    for (int i = 0; i < 8; ++i) {
        const int r = r0 + i;
        float av = 0.f;
#pragma unroll
        for (int ks = 0; ks < KSPLIT; ++ks)
            av += partial[(size_t)ks * (NROWS * HID) + (size_t)r * HID + lane];
        const float xv = xin[(size_t)r * HID + lane];
        float z = 0.f;
#pragma unroll
        for (int j = 0; j < 64; ++j) z += __shfl(av, j) * wsm[j * 64 + lane];
#pragma unroll
        for (int j = 0; j < 64; ++j) z += __shfl(xv, j) * wsm[(64 + j) * 64 + lane];
        xout[(size_t)r * HID + lane] = tanhf(z);
    }
}

extern "C" void kernel_launch(void* const* d_in, const int* in_sizes, int n_in,
                              void* d_out, int out_size, void* d_ws, size_t ws_size,
                              hipStream_t stream) {
    const float* x0 = (const float*)d_in[0];   // user_embs [16384,64]
    const float* adj = (const float*)d_in[1];  // adj [16384,16384]
    const float* W = (const float*)d_in[2];    // W [2,128,64]
    float* out = (float*)d_out;

    char* ws = (char*)d_ws;
    __bf16* Bhi = (__bf16*)(ws);                       // 2 MB
    __bf16* Blo = (__bf16*)(ws + (2u << 20));          // 2 MB
    float* partial = (float*)(ws + (4u << 20));        // 32 MB (8 x 4 MB)
    float* x1 = (float*)(ws + (36u << 20));            // 4 MB

    // hop 0
    pack_b<<<512, 256, 0, stream>>>(x0, Bhi, Blo);
    gemm_partial<<<KSPLIT * 64, 256, 0, stream>>>(adj, Bhi, Blo, partial);
    reduce_dense<<<512, 256, 0, stream>>>(partial, x0, W, x1);
    // hop 1
    pack_b<<<512, 256, 0, stream>>>(x1, Bhi, Blo);
    gemm_partial<<<KSPLIT * 64, 256, 0, stream>>>(adj, Bhi, Blo, partial);
    reduce_dense<<<512, 256, 0, stream>>>(partial, x1, W + 128 * 64, out);
}